// Round 1
// baseline (119.508 us; speedup 1.0000x reference)
//
#include <hip/hip_runtime.h>
#include <hip/hip_bf16.h>

#define IN_DIM 128
#define NUM_CLASSES 2

// Kernel 1: per-node projection.
// p[n] = (dot(x[n], W[0,0:128]), dot(x[n], W[1,0:128]),
//         dot(x[n], W[0,128:256]), dot(x[n], W[1,128:256]))
// One wave per node per grid-stride iteration. Lane i owns dims (2i, 2i+1);
// the 8 W coefficients it needs are loaded once and reused across all nodes.
__global__ __launch_bounds__(256) void node_proj_kernel(
    const float* __restrict__ x,   // [N, 128]
    const float* __restrict__ W,   // [2, 256]
    float4* __restrict__ p,        // [N] packed (a0,a1,d0,d1)
    int n_nodes) {
    const int lane = threadIdx.x & 63;
    const int gwave = (blockIdx.x * blockDim.x + threadIdx.x) >> 6;
    const int nwaves = (gridDim.x * blockDim.x) >> 6;

    // W row-major [c][d] at W[c*256 + d]. Lane's dims: 2*lane, 2*lane+1.
    const int dd = 2 * lane;
    const float2 wa0 = *(const float2*)(W + 0 * 256 + dd);        // class0, first half
    const float2 wa1 = *(const float2*)(W + 1 * 256 + dd);        // class1, first half
    const float2 wd0 = *(const float2*)(W + 0 * 256 + 128 + dd);  // class0, second half
    const float2 wd1 = *(const float2*)(W + 1 * 256 + 128 + dd);  // class1, second half

    for (int n = gwave; n < n_nodes; n += nwaves) {
        const float2 xv = *(const float2*)(x + (size_t)n * IN_DIM + dd);
        float a0 = xv.x * wa0.x + xv.y * wa0.y;
        float a1 = xv.x * wa1.x + xv.y * wa1.y;
        float d0 = xv.x * wd0.x + xv.y * wd0.y;
        float d1 = xv.x * wd1.x + xv.y * wd1.y;
        // 64-lane butterfly reduction of 4 accumulators.
        #pragma unroll
        for (int off = 32; off > 0; off >>= 1) {
            a0 += __shfl_xor(a0, off, 64);
            a1 += __shfl_xor(a1, off, 64);
            d0 += __shfl_xor(d0, off, 64);
            d1 += __shfl_xor(d1, off, 64);
        }
        if (lane == 0) {
            p[n] = make_float4(a0, a1, d0, d1);
        }
    }
}

// Kernel 2: per-edge scoring from the 1.6 MB projection table (L2-resident).
// score[e][c] = p[src].a_c + p[dst].d_c + b[c]
__global__ __launch_bounds__(256) void edge_score_kernel(
    const int* __restrict__ idx,     // [2, E] (src row then dst row), int32
    const float4* __restrict__ p,    // [N]
    const float* __restrict__ b,     // [2]
    float2* __restrict__ out,        // [E] (two classes packed)
    int n_edges) {
    const int e = blockIdx.x * blockDim.x + threadIdx.x;
    if (e >= n_edges) return;
    const int s = idx[e];
    const int d = idx[n_edges + e];
    const float4 ps = p[s];
    const float4 pd = p[d];
    const float b0 = b[0];
    const float b1 = b[1];
    float2 o;
    o.x = ps.x + pd.z + b0;
    o.y = ps.y + pd.w + b1;
    out[e] = o;
}

extern "C" void kernel_launch(void* const* d_in, const int* in_sizes, int n_in,
                              void* d_out, int out_size, void* d_ws, size_t ws_size,
                              hipStream_t stream) {
    const float* x   = (const float*)d_in[0];   // [N, 128]
    const int*   idx = (const int*)d_in[1];     // [2, E] as int32
    const float* W   = (const float*)d_in[2];   // [2, 256]
    const float* b   = (const float*)d_in[3];   // [2]
    float* out = (float*)d_out;                 // [E, 2] fp32

    const int n_nodes = in_sizes[0] / IN_DIM;   // 100000
    const int n_edges = in_sizes[1] / 2;        // 625000

    float4* p = (float4*)d_ws;                  // [n_nodes] = 1.6 MB scratch

    // Kernel 1: 1024 blocks x 256 threads = 4096 waves, ~25 nodes each.
    node_proj_kernel<<<1024, 256, 0, stream>>>(x, W, p, n_nodes);

    // Kernel 2: one thread per edge.
    const int blocks = (n_edges + 255) / 256;
    edge_score_kernel<<<blocks, 256, 0, stream>>>(idx, p, b, (float2*)out, n_edges);
}

// Round 2
// 101.202 us; speedup vs baseline: 1.1809x; 1.1809x over previous
//
#include <hip/hip_runtime.h>
#include <hip/hip_bf16.h>

#define IN_DIM 128

// Kernel 1: per-node projection, quad-split layout.
// p[n] = (dot(x[n], W[0,0:128]), dot(x[n], W[1,0:128]),
//         dot(x[n], W[0,128:256]), dot(x[n], W[1,128:256]))
//
// Lane l -> node (l>>2), dim-slice (l&3)*32..+32. Global load addresses are
// base + 128*l + 16*j (uniform stride-128 pattern, all bytes consumed via L1).
// Each lane keeps 4 partial dots over its 32-dim slice; reduction is only a
// 2-stage intra-quad shuffle (8 shuffles per 16 nodes vs 24 per node before).
// W (512 floats) is staged once per block into LDS with a padded layout:
// table stride 144 floats, sub stride 36 floats -> per ds_read_b128 the four
// sub-groups hit 16 distinct banks (16-lane broadcast within a sub is free).
__global__ __launch_bounds__(256) void node_proj_kernel(
    const float* __restrict__ x,   // [N, 128]
    const float* __restrict__ W,   // [2, 256]
    float4* __restrict__ p,        // [N] packed (a0,a1,d0,d1)
    int n_nodes) {
    __shared__ __align__(16) float wlds[4 * 144];  // [4 tables][4 subs][36]

    // Stage W: element i of W (c = i>>8, d = i&255) goes to table
    // t = (d>>7)*2 + c  (a0,a1,d0,d1), slice sub = (d&127)>>5, kk = d&31.
    for (int i = threadIdx.x; i < 512; i += 256) {
        int c    = i >> 8;
        int d    = i & 255;
        int half = d >> 7;
        int k    = d & 127;
        int sub  = k >> 5;
        int kk   = k & 31;
        wlds[(half * 2 + c) * 144 + sub * 36 + kk] = W[i];
    }
    __syncthreads();

    const int lane = threadIdx.x & 63;
    const int sub  = lane & 3;        // which 32-dim slice
    const int nl   = lane >> 2;       // node within wave (0..15)
    const int wave = threadIdx.x >> 6;
    const int node = (blockIdx.x * 4 + wave) * 16 + nl;

    if (node < n_nodes) {
        const float* xb = x + (size_t)node * IN_DIM + sub * 32;
        const float* wt = wlds + sub * 36;

        float a0 = 0.f, a1 = 0.f, d0 = 0.f, d1 = 0.f;
        #pragma unroll
        for (int j = 0; j < 8; ++j) {
            const float4 xv = *(const float4*)(xb + j * 4);
            const float4 w0 = *(const float4*)(wt + 0 * 144 + j * 4);
            const float4 w1 = *(const float4*)(wt + 1 * 144 + j * 4);
            const float4 w2 = *(const float4*)(wt + 2 * 144 + j * 4);
            const float4 w3 = *(const float4*)(wt + 3 * 144 + j * 4);
            a0 += xv.x * w0.x + xv.y * w0.y + xv.z * w0.z + xv.w * w0.w;
            a1 += xv.x * w1.x + xv.y * w1.y + xv.z * w1.z + xv.w * w1.w;
            d0 += xv.x * w2.x + xv.y * w2.y + xv.z * w2.z + xv.w * w2.w;
            d1 += xv.x * w3.x + xv.y * w3.y + xv.z * w3.z + xv.w * w3.w;
        }

        // 2-stage intra-quad butterfly (lanes of a quad share `node`).
        a0 += __shfl_xor(a0, 1, 64);
        a1 += __shfl_xor(a1, 1, 64);
        d0 += __shfl_xor(d0, 1, 64);
        d1 += __shfl_xor(d1, 1, 64);
        a0 += __shfl_xor(a0, 2, 64);
        a1 += __shfl_xor(a1, 2, 64);
        d0 += __shfl_xor(d0, 2, 64);
        d1 += __shfl_xor(d1, 2, 64);

        if (sub == 0) {
            p[node] = make_float4(a0, a1, d0, d1);
        }
    }
}

// Kernel 2: per-edge scoring from the 1.6 MB projection table (L2-resident).
// score[e][c] = p[src].a_c + p[dst].d_c + b[c]
__global__ __launch_bounds__(256) void edge_score_kernel(
    const int* __restrict__ idx,     // [2, E] (src row then dst row), int32
    const float4* __restrict__ p,    // [N]
    const float* __restrict__ b,     // [2]
    float2* __restrict__ out,        // [E] (two classes packed)
    int n_edges) {
    const int e = blockIdx.x * blockDim.x + threadIdx.x;
    if (e >= n_edges) return;
    const int s = idx[e];
    const int d = idx[n_edges + e];
    const float4 ps = p[s];
    const float4 pd = p[d];
    const float b0 = b[0];
    const float b1 = b[1];
    float2 o;
    o.x = ps.x + pd.z + b0;
    o.y = ps.y + pd.w + b1;
    out[e] = o;
}

extern "C" void kernel_launch(void* const* d_in, const int* in_sizes, int n_in,
                              void* d_out, int out_size, void* d_ws, size_t ws_size,
                              hipStream_t stream) {
    const float* x   = (const float*)d_in[0];   // [N, 128]
    const int*   idx = (const int*)d_in[1];     // [2, E] as int32
    const float* W   = (const float*)d_in[2];   // [2, 256]
    const float* b   = (const float*)d_in[3];   // [2]
    float* out = (float*)d_out;                 // [E, 2] fp32

    const int n_nodes = in_sizes[0] / IN_DIM;   // 100000
    const int n_edges = in_sizes[1] / 2;        // 625000

    float4* p = (float4*)d_ws;                  // [n_nodes] = 1.6 MB scratch

    // Kernel 1: 64 nodes per 256-thread block (16 per wave).
    const int blocks1 = (n_nodes + 63) / 64;
    node_proj_kernel<<<blocks1, 256, 0, stream>>>(x, W, p, n_nodes);

    // Kernel 2: one thread per edge.
    const int blocks2 = (n_edges + 255) / 256;
    edge_score_kernel<<<blocks2, 256, 0, stream>>>(idx, p, b, (float2*)out, n_edges);
}

// Round 3
// 100.509 us; speedup vs baseline: 1.1890x; 1.0069x over previous
//
#include <hip/hip_runtime.h>
#include <hip/hip_bf16.h>

#define IN_DIM 128

// Kernel 1: per-node projection, quad-split layout.
// pa[n] = (dot(x[n], W[0,0:128]), dot(x[n], W[1,0:128]))   -- used by src side
// pd[n] = (dot(x[n], W[0,128:256]), dot(x[n], W[1,128:256])) -- used by dst side
//
// Lane l -> node (l>>2), dim-slice (l&3)*32..+32. Each lane keeps 4 partial
// dots over its 32-dim slice; reduction is a 2-stage intra-quad butterfly
// (all 4 lanes end with full sums; lane sub==0 writes pa, sub==1 writes pd).
// W (512 floats) staged once per block into padded LDS (table stride 144,
// sub stride 36 -> conflict-free ds_read_b128 with 16-lane broadcast).
__global__ __launch_bounds__(256) void node_proj_kernel(
    const float* __restrict__ x,   // [N, 128]
    const float* __restrict__ W,   // [2, 256]
    float2* __restrict__ pa,       // [N] (a0,a1)
    float2* __restrict__ pd,       // [N] (d0,d1)
    int n_nodes) {
    __shared__ __align__(16) float wlds[4 * 144];  // [4 tables][4 subs][36]

    for (int i = threadIdx.x; i < 512; i += 256) {
        int c    = i >> 8;
        int d    = i & 255;
        int half = d >> 7;
        int k    = d & 127;
        int sub  = k >> 5;
        int kk   = k & 31;
        wlds[(half * 2 + c) * 144 + sub * 36 + kk] = W[i];
    }
    __syncthreads();

    const int lane = threadIdx.x & 63;
    const int sub  = lane & 3;        // which 32-dim slice
    const int nl   = lane >> 2;       // node within wave (0..15)
    const int wave = threadIdx.x >> 6;
    const int node = (blockIdx.x * 4 + wave) * 16 + nl;

    if (node < n_nodes) {
        const float* xb = x + (size_t)node * IN_DIM + sub * 32;
        const float* wt = wlds + sub * 36;

        float a0 = 0.f, a1 = 0.f, d0 = 0.f, d1 = 0.f;
        #pragma unroll
        for (int j = 0; j < 8; ++j) {
            const float4 xv = *(const float4*)(xb + j * 4);
            const float4 w0 = *(const float4*)(wt + 0 * 144 + j * 4);
            const float4 w1 = *(const float4*)(wt + 1 * 144 + j * 4);
            const float4 w2 = *(const float4*)(wt + 2 * 144 + j * 4);
            const float4 w3 = *(const float4*)(wt + 3 * 144 + j * 4);
            a0 += xv.x * w0.x + xv.y * w0.y + xv.z * w0.z + xv.w * w0.w;
            a1 += xv.x * w1.x + xv.y * w1.y + xv.z * w1.z + xv.w * w1.w;
            d0 += xv.x * w2.x + xv.y * w2.y + xv.z * w2.z + xv.w * w2.w;
            d1 += xv.x * w3.x + xv.y * w3.y + xv.z * w3.z + xv.w * w3.w;
        }

        // 2-stage intra-quad butterfly: afterwards ALL quad lanes hold sums.
        a0 += __shfl_xor(a0, 1, 64);
        a1 += __shfl_xor(a1, 1, 64);
        d0 += __shfl_xor(d0, 1, 64);
        d1 += __shfl_xor(d1, 1, 64);
        a0 += __shfl_xor(a0, 2, 64);
        a1 += __shfl_xor(a1, 2, 64);
        d0 += __shfl_xor(d0, 2, 64);
        d1 += __shfl_xor(d1, 2, 64);

        if (sub == 0) pa[node] = make_float2(a0, a1);
        if (sub == 1) pd[node] = make_float2(d0, d1);
    }
}

// Kernel 2: per-edge scoring from two 0.8 MB float2 tables (L2-resident).
// score[e][c] = pa[src[e]].c + pd[dst[e]].c + b[c]
// 2 edges per thread: int2 index loads, 4x 8B gathers, one float4 store.
__global__ __launch_bounds__(256) void edge_score_kernel(
    const int* __restrict__ idx,     // [2, E] (src row then dst row), int32
    const float2* __restrict__ pa,   // [N]
    const float2* __restrict__ pd,   // [N]
    const float* __restrict__ b,     // [2]
    float4* __restrict__ out,        // [E/2] (2 edges x 2 classes)
    int n_edges) {
    const int t = blockIdx.x * blockDim.x + threadIdx.x;
    const int e = t * 2;
    if (e >= n_edges) return;
    const int2 s = *(const int2*)(idx + e);             // src[e], src[e+1]
    const int2 d = *(const int2*)(idx + n_edges + e);   // dst[e], dst[e+1]
    const float2 ps0 = pa[s.x];
    const float2 ps1 = pa[s.y];
    const float2 pd0 = pd[d.x];
    const float2 pd1 = pd[d.y];
    const float b0 = b[0];
    const float b1 = b[1];
    float4 o;
    o.x = ps0.x + pd0.x + b0;
    o.y = ps0.y + pd0.y + b1;
    o.z = ps1.x + pd1.x + b0;
    o.w = ps1.y + pd1.y + b1;
    out[t] = o;
}

extern "C" void kernel_launch(void* const* d_in, const int* in_sizes, int n_in,
                              void* d_out, int out_size, void* d_ws, size_t ws_size,
                              hipStream_t stream) {
    const float* x   = (const float*)d_in[0];   // [N, 128]
    const int*   idx = (const int*)d_in[1];     // [2, E] as int32
    const float* W   = (const float*)d_in[2];   // [2, 256]
    const float* b   = (const float*)d_in[3];   // [2]
    float* out = (float*)d_out;                 // [E, 2] fp32

    const int n_nodes = in_sizes[0] / IN_DIM;   // 100000
    const int n_edges = in_sizes[1] / 2;        // 625000

    float2* pa = (float2*)d_ws;                       // 800 KB
    float2* pd = (float2*)((char*)d_ws + (size_t)n_nodes * sizeof(float2));

    // Kernel 1: 64 nodes per 256-thread block (16 per wave).
    const int blocks1 = (n_nodes + 63) / 64;
    node_proj_kernel<<<blocks1, 256, 0, stream>>>(x, W, pa, pd, n_nodes);

    // Kernel 2: two edges per thread.
    const int n_pairs = (n_edges + 1) / 2;
    const int blocks2 = (n_pairs + 255) / 256;
    edge_score_kernel<<<blocks2, 256, 0, stream>>>(idx, pa, pd, b, (float4*)out, n_edges);
}